// Round 1
// baseline (574.490 us; speedup 1.0000x reference)
//
#include <hip/hip_runtime.h>
#include <hip/hip_bf16.h>

#define DIM 32
#define INDIM 5

// ---------------- CSR build ----------------

__global__ void count_kernel(const int* __restrict__ dst, int* __restrict__ cnt, int e) {
    int i = blockIdx.x * 256 + threadIdx.x;
    if (i < e) atomicAdd(&cnt[dst[i]], 1);
}

__global__ void block_sum_kernel(const int* __restrict__ cnt, int* __restrict__ bsum, int n) {
    __shared__ int s[256];
    int t = threadIdx.x;
    int i = blockIdx.x * 256 + t;
    s[t] = (i < n) ? cnt[i] : 0;
    __syncthreads();
    for (int off = 128; off > 0; off >>= 1) {
        if (t < off) s[t] += s[t + off];
        __syncthreads();
    }
    if (t == 0) bsum[blockIdx.x] = s[0];
}

// single block: exclusive scan of bsum[0..nb), nb <= 512
__global__ void scan_bsum_kernel(int* bsum, int nb) {
    __shared__ int s[512];
    int t = threadIdx.x;
    int v = (t < nb) ? bsum[t] : 0;
    s[t] = v;
    __syncthreads();
    for (int off = 1; off < 512; off <<= 1) {
        int add = (t >= off) ? s[t - off] : 0;
        __syncthreads();
        s[t] += add;
        __syncthreads();
    }
    if (t < nb) bsum[t] = s[t] - v;  // exclusive
}

// per-block exclusive scan + block offset; writes row_ptr and resets cnt to cursor
__global__ void scan_final_kernel(int* __restrict__ cnt_cursor, int* __restrict__ row_ptr,
                                  const int* __restrict__ bscan, int n, int e_total) {
    __shared__ int s[256];
    int t = threadIdx.x;
    int i = blockIdx.x * 256 + t;
    int v = (i < n) ? cnt_cursor[i] : 0;
    s[t] = v;
    __syncthreads();
    for (int off = 1; off < 256; off <<= 1) {
        int add = (t >= off) ? s[t - off] : 0;
        __syncthreads();
        s[t] += add;
        __syncthreads();
    }
    int excl = s[t] - v + bscan[blockIdx.x];
    if (i < n) {
        row_ptr[i] = excl;
        cnt_cursor[i] = excl;  // cursor for fill
    }
    if (i == 0) row_ptr[n] = e_total;
}

__global__ void fill_kernel(const int* __restrict__ src, const int* __restrict__ dst,
                            int* __restrict__ cursor, int* __restrict__ esrc, int e) {
    int i = blockIdx.x * 256 + threadIdx.x;
    if (i < e) {
        int d = dst[i];
        int pos = atomicAdd(&cursor[d], 1);
        esrc[pos] = src[i];
    }
}

// ---------------- input projection: h = x @ w_in.T + b_in ----------------

__global__ void input_proj_kernel(const float* __restrict__ x, const float* __restrict__ w_in,
                                  const float* __restrict__ b_in, float* __restrict__ h, int n) {
    __shared__ float sw[DIM * INDIM];
    __shared__ float sb[DIM];
    int t = threadIdx.x;
    if (t < DIM * INDIM) sw[t] = w_in[t];
    if (t < DIM) sb[t] = b_in[t];
    __syncthreads();
    int idx = blockIdx.x * 256 + t;
    int node = idx >> 5;
    int d = idx & 31;
    if (node < n) {
        const float* xr = x + (size_t)node * INDIM;
        float acc = sb[d];
#pragma unroll
        for (int k = 0; k < INDIM; k++) acc = fmaf(xr[k], sw[d * INDIM + k], acc);
        h[(size_t)node * DIM + d] = acc;
    }
}

// ---------------- fused layer: mean-aggregate + SAGEConv + ReLU + LayerNorm ----------------
// half-wave (32 lanes) per node; 8 nodes per 256-thread block

__global__ __launch_bounds__(256) void layer_kernel(
    const float* __restrict__ h_in, float* __restrict__ h_out,
    const int* __restrict__ row_ptr, const int* __restrict__ esrc,
    const float* __restrict__ wl, const float* __restrict__ bl,
    const float* __restrict__ wr, const float* __restrict__ gamma,
    const float* __restrict__ beta, int n) {
    __shared__ float sWl[DIM][DIM + 1];  // +1 pad: bank-conflict-free per-lane-row reads
    __shared__ float sWr[DIM][DIM + 1];
    __shared__ float sB[DIM], sG[DIM], sBe[DIM];

    int t = threadIdx.x;
    for (int i = t; i < DIM * DIM; i += 256) {
        sWl[i >> 5][i & 31] = wl[i];
        sWr[i >> 5][i & 31] = wr[i];
    }
    if (t < DIM) {
        sB[t] = bl[t];
        sG[t] = gamma[t];
        sBe[t] = beta[t];
    }
    __syncthreads();

    int lane = t & 31;
    int node = blockIdx.x * 8 + (t >> 5);
    if (node >= n) return;

    float hp = h_in[(size_t)node * DIM + lane];
    int rs = row_ptr[node];
    int re = row_ptr[node + 1];

    // gather + sum neighbors: 32 edge ids loaded coalesced, broadcast via shfl
    float acc = 0.f;
    for (int j = rs; j < re; j += 32) {
        int m = re - j;
        if (m > 32) m = 32;
        int se = (lane < m) ? esrc[j + lane] : 0;
        for (int q = 0; q < m; q++) {
            int s = __shfl(se, q, 32);
            acc += h_in[(size_t)s * DIM + lane];
        }
    }
    float inv = 1.f / fmaxf((float)(re - rs), 1.f);
    float agg = acc * inv;

    // out[lane] = b + sum_k agg[k]*Wl[lane][k] + hp[k]*Wr[lane][k]
    float out = sB[lane];
#pragma unroll
    for (int k = 0; k < DIM; k++) {
        float ak = __shfl(agg, k, 32);
        float hk = __shfl(hp, k, 32);
        out = fmaf(ak, sWl[lane][k], out);
        out = fmaf(hk, sWr[lane][k], out);
    }

    // ReLU + LayerNorm over 32 dims
    out = fmaxf(out, 0.f);
    float sum = out, sq = out * out;
#pragma unroll
    for (int off = 16; off > 0; off >>= 1) {
        sum += __shfl_xor(sum, off, 32);
        sq += __shfl_xor(sq, off, 32);
    }
    float mu = sum * (1.f / 32.f);
    float var = fmaxf(sq * (1.f / 32.f) - mu * mu, 0.f);
    float r = rsqrtf(var + 1e-5f);
    h_out[(size_t)node * DIM + lane] = (out - mu) * r * sG[lane] + sBe[lane];
}

// ---------------- launch ----------------

extern "C" void kernel_launch(void* const* d_in, const int* in_sizes, int n_in,
                              void* d_out, int out_size, void* d_ws, size_t ws_size,
                              hipStream_t stream) {
    const float* x = (const float*)d_in[0];
    const int* ei = (const int*)d_in[1];
    const float* w_in = (const float*)d_in[2];
    const float* b_in = (const float*)d_in[3];
    const float* w_l = (const float*)d_in[4];
    const float* b_l = (const float*)d_in[5];
    const float* w_r = (const float*)d_in[6];
    const float* gamma = (const float*)d_in[7];
    const float* beta = (const float*)d_in[8];

    int n = in_sizes[0] / INDIM;
    int e = in_sizes[1] / 2;
    int L = in_sizes[4] / (DIM * DIM);
    const int* src = ei;
    const int* dst = ei + e;

    // workspace carve
    char* w = (char*)d_ws;
    int* cnt = (int*)w;          w += (size_t)(n + 1) * 4;
    int* row_ptr = (int*)w;      w += (size_t)(n + 1) * 4;
    int* esrc = (int*)w;         w += (size_t)e * 4;
    int* bsum = (int*)w;         w += 4096;
    float* h_a = (float*)w;      w += (size_t)n * DIM * 4;

    int nbE = (e + 255) / 256;
    int nbN = (n + 255) / 256;  // 391 for N=100000, fits single-block 512 scan

    hipMemsetAsync(cnt, 0, (size_t)n * 4, stream);
    count_kernel<<<nbE, 256, 0, stream>>>(dst, cnt, e);
    block_sum_kernel<<<nbN, 256, 0, stream>>>(cnt, bsum, n);
    scan_bsum_kernel<<<1, 512, 0, stream>>>(bsum, nbN);
    scan_final_kernel<<<nbN, 256, 0, stream>>>(cnt, row_ptr, bsum, n, e);
    fill_kernel<<<nbE, 256, 0, stream>>>(src, dst, cnt, esrc, e);

    input_proj_kernel<<<(n * DIM + 255) / 256, 256, 0, stream>>>(x, w_in, b_in, h_a, n);

    // ping-pong: buffers[0]=h_a, buffers[1]=d_out; layer i reads i%2, writes (i+1)%2.
    // L=3 (odd) -> final layer writes d_out.
    float* bufs[2] = {h_a, (float*)d_out};
    int nbL = (n + 7) / 8;
    for (int i = 0; i < L; i++) {
        const float* hin = bufs[i & 1];
        float* hout = bufs[(i + 1) & 1];
        layer_kernel<<<nbL, 256, 0, stream>>>(hin, hout, row_ptr, esrc,
                                              w_l + (size_t)i * DIM * DIM,
                                              b_l + (size_t)i * DIM,
                                              w_r + (size_t)i * DIM * DIM,
                                              gamma, beta, n);
    }
}

// Round 2
// 394.874 us; speedup vs baseline: 1.4549x; 1.4549x over previous
//
#include <hip/hip_runtime.h>
#include <hip/hip_bf16.h>

#define DIM 32
#define INDIM 5
#define EPB 4096      // edges per block in bucketing passes
#define NBMAX 512     // max buckets (n <= 131072)
#define CAP 8192      // P2 LDS staging capacity (mean bucket load ~5120)

// ---------------- P0: bucket sizes ----------------

__global__ __launch_bounds__(256) void bucket_count_kernel(const int* __restrict__ dst,
                                                           int* __restrict__ bcnt, int e, int nb) {
    __shared__ int hist[NBMAX];
    int t = threadIdx.x;
    for (int i = t; i < nb; i += 256) hist[i] = 0;
    __syncthreads();
    int base = blockIdx.x * EPB;
    for (int k = 0; k < EPB; k += 256) {
        int i = base + k + t;
        if (i < e) atomicAdd(&hist[dst[i] >> 8], 1);
    }
    __syncthreads();
    for (int i = t; i < nb; i += 256) {
        int h = hist[i];
        if (h) atomicAdd(&bcnt[i], h);
    }
}

// ---------------- scan of bucket sizes (single block) ----------------

__global__ void bucket_scan_kernel(const int* __restrict__ bcnt, int* __restrict__ bbase,
                                   int* __restrict__ bcur, int* __restrict__ row_ptr,
                                   int nb, int n, int e) {
    __shared__ int s[512];
    int t = threadIdx.x;
    int v = (t < nb) ? bcnt[t] : 0;
    s[t] = v;
    __syncthreads();
    for (int o = 1; o < 512; o <<= 1) {
        int a = (t >= o) ? s[t - o] : 0;
        __syncthreads();
        s[t] += a;
        __syncthreads();
    }
    if (t < nb) {
        int excl = s[t] - v;
        bbase[t] = excl;
        bcur[t] = excl;
    }
    if (t == 0) {
        bbase[nb] = e;
        row_ptr[n] = e;
    }
}

// ---------------- P1: bucketed scatter of packed edges ----------------
// packed word: (src << 8) | (dst & 255)

__global__ __launch_bounds__(256) void bucket_fill_kernel(const int* __restrict__ src,
                                                          const int* __restrict__ dst,
                                                          int* __restrict__ bcur,
                                                          unsigned* __restrict__ packed,
                                                          int e, int nb) {
    __shared__ unsigned sw[EPB];
    __shared__ unsigned short sb[EPB];
    __shared__ int hist[NBMAX];
    __shared__ int rbase[NBMAX];
    int t = threadIdx.x;
    for (int i = t; i < nb; i += 256) hist[i] = 0;
    __syncthreads();
    int base = blockIdx.x * EPB;
    for (int k = 0; k < EPB; k += 256) {
        int i = base + k + t;
        if (i < e) {
            int s = src[i];
            int d = dst[i];
            int b = d >> 8;
            sw[k + t] = ((unsigned)s << 8) | (unsigned)(d & 255);
            sb[k + t] = (unsigned short)b;
            atomicAdd(&hist[b], 1);
        }
    }
    __syncthreads();
    for (int i = t; i < nb; i += 256) {
        int h = hist[i];
        rbase[i] = h ? atomicAdd(&bcur[i], h) : 0;
        hist[i] = 0;  // reuse as rank counter
    }
    __syncthreads();
    for (int k = 0; k < EPB; k += 256) {
        int i = base + k + t;
        if (i < e) {
            int b = sb[k + t];
            int r = atomicAdd(&hist[b], 1);
            packed[rbase[b] + r] = sw[k + t];
        }
    }
}

// ---------------- P2: per-bucket counting sort -> exact CSR ----------------

__global__ __launch_bounds__(256) void csr_build_kernel(const unsigned* __restrict__ packed,
                                                        const int* __restrict__ bbase,
                                                        int* __restrict__ row_ptr,
                                                        int* __restrict__ esrc, int n) {
    __shared__ unsigned ew[CAP];
    __shared__ int h2[256];
    __shared__ int off[256];
    int b = blockIdx.x;
    int base = bbase[b];
    int cnt = bbase[b + 1] - base;
    int t = threadIdx.x;
    h2[t] = 0;
    __syncthreads();
    bool staged = (cnt <= CAP);
    for (int i = t; i < cnt; i += 256) {
        unsigned w = packed[base + i];
        if (staged) ew[i] = w;
        atomicAdd(&h2[w & 255], 1);
    }
    __syncthreads();
    // exclusive scan of h2 over 256 entries
    int v = h2[t];
    off[t] = v;
    __syncthreads();
    for (int o = 1; o < 256; o <<= 1) {
        int a = (t >= o) ? off[t - o] : 0;
        __syncthreads();
        off[t] += a;
        __syncthreads();
    }
    int excl = off[t] - v;
    __syncthreads();
    off[t] = excl;
    h2[t] = 0;  // reuse as rank counter
    __syncthreads();
    int node = b * 256 + t;
    if (node < n) row_ptr[node] = base + excl;
    for (int i = t; i < cnt; i += 256) {
        unsigned w = staged ? ew[i] : packed[base + i];
        int dl = w & 255;
        int r = atomicAdd(&h2[dl], 1);
        esrc[base + off[dl] + r] = (int)(w >> 8);
    }
}

// ---------------- input projection: h = x @ w_in.T + b_in ----------------

__global__ void input_proj_kernel(const float* __restrict__ x, const float* __restrict__ w_in,
                                  const float* __restrict__ b_in, float* __restrict__ h, int n) {
    __shared__ float sw[DIM * INDIM];
    __shared__ float sb[DIM];
    int t = threadIdx.x;
    if (t < DIM * INDIM) sw[t] = w_in[t];
    if (t < DIM) sb[t] = b_in[t];
    __syncthreads();
    int idx = blockIdx.x * 256 + t;
    int node = idx >> 5;
    int d = idx & 31;
    if (node < n) {
        const float* xr = x + (size_t)node * INDIM;
        float acc = sb[d];
#pragma unroll
        for (int k = 0; k < INDIM; k++) acc = fmaf(xr[k], sw[d * INDIM + k], acc);
        h[(size_t)node * DIM + d] = acc;
    }
}

// ---------------- fused layer: mean-aggregate + SAGEConv + ReLU + LayerNorm ----------------
// half-wave (32 lanes) per node; 8 nodes per 256-thread block

__global__ __launch_bounds__(256) void layer_kernel(
    const float* __restrict__ h_in, float* __restrict__ h_out,
    const int* __restrict__ row_ptr, const int* __restrict__ esrc,
    const float* __restrict__ wl, const float* __restrict__ bl,
    const float* __restrict__ wr, const float* __restrict__ gamma,
    const float* __restrict__ beta, int n) {
    __shared__ float sWl[DIM][DIM + 1];
    __shared__ float sWr[DIM][DIM + 1];
    __shared__ float sB[DIM], sG[DIM], sBe[DIM];

    int t = threadIdx.x;
    for (int i = t; i < DIM * DIM; i += 256) {
        sWl[i >> 5][i & 31] = wl[i];
        sWr[i >> 5][i & 31] = wr[i];
    }
    if (t < DIM) {
        sB[t] = bl[t];
        sG[t] = gamma[t];
        sBe[t] = beta[t];
    }
    __syncthreads();

    int lane = t & 31;
    int node = blockIdx.x * 8 + (t >> 5);
    if (node >= n) return;

    float hp = h_in[(size_t)node * DIM + lane];
    int rs = row_ptr[node];
    int re = row_ptr[node + 1];

    float acc = 0.f;
    for (int j = rs; j < re; j += 32) {
        int m = re - j;
        if (m > 32) m = 32;
        int se = (lane < m) ? esrc[j + lane] : 0;
        for (int q = 0; q < m; q++) {
            int s = __shfl(se, q, 32);
            acc += h_in[(size_t)s * DIM + lane];
        }
    }
    float inv = 1.f / fmaxf((float)(re - rs), 1.f);
    float agg = acc * inv;

    float out = sB[lane];
#pragma unroll
    for (int k = 0; k < DIM; k++) {
        float ak = __shfl(agg, k, 32);
        float hk = __shfl(hp, k, 32);
        out = fmaf(ak, sWl[lane][k], out);
        out = fmaf(hk, sWr[lane][k], out);
    }

    out = fmaxf(out, 0.f);
    float sum = out, sq = out * out;
#pragma unroll
    for (int off = 16; off > 0; off >>= 1) {
        sum += __shfl_xor(sum, off, 32);
        sq += __shfl_xor(sq, off, 32);
    }
    float mu = sum * (1.f / 32.f);
    float var = fmaxf(sq * (1.f / 32.f) - mu * mu, 0.f);
    float r = rsqrtf(var + 1e-5f);
    h_out[(size_t)node * DIM + lane] = (out - mu) * r * sG[lane] + sBe[lane];
}

// ---------------- launch ----------------

extern "C" void kernel_launch(void* const* d_in, const int* in_sizes, int n_in,
                              void* d_out, int out_size, void* d_ws, size_t ws_size,
                              hipStream_t stream) {
    const float* x = (const float*)d_in[0];
    const int* ei = (const int*)d_in[1];
    const float* w_in = (const float*)d_in[2];
    const float* b_in = (const float*)d_in[3];
    const float* w_l = (const float*)d_in[4];
    const float* b_l = (const float*)d_in[5];
    const float* w_r = (const float*)d_in[6];
    const float* gamma = (const float*)d_in[7];
    const float* beta = (const float*)d_in[8];

    int n = in_sizes[0] / INDIM;
    int e = in_sizes[1] / 2;
    int L = in_sizes[4] / (DIM * DIM);
    const int* src = ei;
    const int* dst = ei + e;
    int nb = (n + 255) >> 8;  // 391 buckets of 256 nodes

    // workspace carve
    char* w = (char*)d_ws;
    int* bcnt = (int*)w;      w += (size_t)NBMAX * 4;
    int* bbase = (int*)w;     w += (size_t)(NBMAX + 1) * 4;
    int* bcur = (int*)w;      w += (size_t)NBMAX * 4;
    int* row_ptr = (int*)w;   w += (size_t)(n + 1) * 4;
    int* esrc = (int*)w;      w += (size_t)e * 4;
    float* h_a = (float*)w;   w += (size_t)n * DIM * 4;
    // packed aliases h_a's storage: packed is dead before input_proj writes h_a
    unsigned* packed = (unsigned*)h_a;

    int nbE = (e + EPB - 1) / EPB;

    hipMemsetAsync(bcnt, 0, (size_t)nb * 4, stream);
    bucket_count_kernel<<<nbE, 256, 0, stream>>>(dst, bcnt, e, nb);
    bucket_scan_kernel<<<1, 512, 0, stream>>>(bcnt, bbase, bcur, row_ptr, nb, n, e);
    bucket_fill_kernel<<<nbE, 256, 0, stream>>>(src, dst, bcur, packed, e, nb);
    csr_build_kernel<<<nb, 256, 0, stream>>>(packed, bbase, row_ptr, esrc, n);

    input_proj_kernel<<<(n * DIM + 255) / 256, 256, 0, stream>>>(x, w_in, b_in, h_a, n);

    // ping-pong: L=3 (odd) -> final layer writes d_out.
    float* bufs[2] = {h_a, (float*)d_out};
    int nbL = (n + 7) / 8;
    for (int i = 0; i < L; i++) {
        const float* hin = bufs[i & 1];
        float* hout = bufs[(i + 1) & 1];
        layer_kernel<<<nbL, 256, 0, stream>>>(hin, hout, row_ptr, esrc,
                                              w_l + (size_t)i * DIM * DIM,
                                              b_l + (size_t)i * DIM,
                                              w_r + (size_t)i * DIM * DIM,
                                              gamma, beta, n);
    }
}

// Round 3
// 353.269 us; speedup vs baseline: 1.6262x; 1.1178x over previous
//
#include <hip/hip_runtime.h>
#include <hip/hip_bf16.h>

#define DIM 32
#define INDIM 5
#define EPB 4096      // edges per block in bucketing passes
#define NBMAX 512     // max buckets (n <= 131072)
#define CAP 8192      // P2 LDS staging capacity (mean bucket load ~5120)

// bf16 helpers (bit-level, round-to-nearest-even)
__device__ __forceinline__ unsigned short f2bf(float f) {
    unsigned u = __float_as_uint(f);
    u += 0x7FFFu + ((u >> 16) & 1u);
    return (unsigned short)(u >> 16);
}
__device__ __forceinline__ float bf2f_lo(unsigned u) { return __uint_as_float(u << 16); }
__device__ __forceinline__ float bf2f_hi(unsigned u) { return __uint_as_float(u & 0xFFFF0000u); }

// ---------------- P0: bucket sizes ----------------

__global__ __launch_bounds__(256) void bucket_count_kernel(const int* __restrict__ dst,
                                                           int* __restrict__ bcnt, int e, int nb) {
    __shared__ int hist[NBMAX];
    int t = threadIdx.x;
    for (int i = t; i < nb; i += 256) hist[i] = 0;
    __syncthreads();
    int base = blockIdx.x * EPB;
    for (int k = 0; k < EPB; k += 256) {
        int i = base + k + t;
        if (i < e) atomicAdd(&hist[dst[i] >> 8], 1);
    }
    __syncthreads();
    for (int i = t; i < nb; i += 256) {
        int h = hist[i];
        if (h) atomicAdd(&bcnt[i], h);
    }
}

// ---------------- scan of bucket sizes (single block) ----------------

__global__ void bucket_scan_kernel(const int* __restrict__ bcnt, int* __restrict__ bbase,
                                   int* __restrict__ bcur, int* __restrict__ row_ptr,
                                   int nb, int n, int e) {
    __shared__ int s[512];
    int t = threadIdx.x;
    int v = (t < nb) ? bcnt[t] : 0;
    s[t] = v;
    __syncthreads();
    for (int o = 1; o < 512; o <<= 1) {
        int a = (t >= o) ? s[t - o] : 0;
        __syncthreads();
        s[t] += a;
        __syncthreads();
    }
    if (t < nb) {
        int excl = s[t] - v;
        bbase[t] = excl;
        bcur[t] = excl;
    }
    if (t == 0) {
        bbase[nb] = e;
        row_ptr[n] = e;
    }
}

// ---------------- P1: bucketed scatter of packed edges ----------------
// packed word: (src << 8) | (dst & 255)

__global__ __launch_bounds__(256) void bucket_fill_kernel(const int* __restrict__ src,
                                                          const int* __restrict__ dst,
                                                          int* __restrict__ bcur,
                                                          unsigned* __restrict__ packed,
                                                          int e, int nb) {
    __shared__ unsigned sw[EPB];
    __shared__ unsigned short sb[EPB];
    __shared__ int hist[NBMAX];
    __shared__ int rbase[NBMAX];
    int t = threadIdx.x;
    for (int i = t; i < nb; i += 256) hist[i] = 0;
    __syncthreads();
    int base = blockIdx.x * EPB;
    for (int k = 0; k < EPB; k += 256) {
        int i = base + k + t;
        if (i < e) {
            int s = src[i];
            int d = dst[i];
            int b = d >> 8;
            sw[k + t] = ((unsigned)s << 8) | (unsigned)(d & 255);
            sb[k + t] = (unsigned short)b;
            atomicAdd(&hist[b], 1);
        }
    }
    __syncthreads();
    for (int i = t; i < nb; i += 256) {
        int h = hist[i];
        rbase[i] = h ? atomicAdd(&bcur[i], h) : 0;
        hist[i] = 0;  // reuse as rank counter
    }
    __syncthreads();
    for (int k = 0; k < EPB; k += 256) {
        int i = base + k + t;
        if (i < e) {
            int b = sb[k + t];
            int r = atomicAdd(&hist[b], 1);
            packed[rbase[b] + r] = sw[k + t];
        }
    }
}

// ---------------- P2: per-bucket counting sort -> exact CSR ----------------

__global__ __launch_bounds__(256) void csr_build_kernel(const unsigned* __restrict__ packed,
                                                        const int* __restrict__ bbase,
                                                        int* __restrict__ row_ptr,
                                                        int* __restrict__ esrc, int n) {
    __shared__ unsigned ew[CAP];
    __shared__ int h2[256];
    __shared__ int off[256];
    int b = blockIdx.x;
    int base = bbase[b];
    int cnt = bbase[b + 1] - base;
    int t = threadIdx.x;
    h2[t] = 0;
    __syncthreads();
    bool staged = (cnt <= CAP);
    for (int i = t; i < cnt; i += 256) {
        unsigned w = packed[base + i];
        if (staged) ew[i] = w;
        atomicAdd(&h2[w & 255], 1);
    }
    __syncthreads();
    int v = h2[t];
    off[t] = v;
    __syncthreads();
    for (int o = 1; o < 256; o <<= 1) {
        int a = (t >= o) ? off[t - o] : 0;
        __syncthreads();
        off[t] += a;
        __syncthreads();
    }
    int excl = off[t] - v;
    __syncthreads();
    off[t] = excl;
    h2[t] = 0;  // reuse as rank counter
    __syncthreads();
    int node = b * 256 + t;
    if (node < n) row_ptr[node] = base + excl;
    for (int i = t; i < cnt; i += 256) {
        unsigned w = staged ? ew[i] : packed[base + i];
        int dl = w & 255;
        int r = atomicAdd(&h2[dl], 1);
        esrc[base + off[dl] + r] = (int)(w >> 8);
    }
}

// ---------------- input projection: h = x @ w_in.T + b_in (bf16 out) ----------------

__global__ void input_proj_kernel(const float* __restrict__ x, const float* __restrict__ w_in,
                                  const float* __restrict__ b_in,
                                  unsigned short* __restrict__ h, int n) {
    __shared__ float sw[DIM * INDIM];
    __shared__ float sb[DIM];
    int t = threadIdx.x;
    if (t < DIM * INDIM) sw[t] = w_in[t];
    if (t < DIM) sb[t] = b_in[t];
    __syncthreads();
    int idx = blockIdx.x * 256 + t;
    int node = idx >> 5;
    int d = idx & 31;
    if (node < n) {
        const float* xr = x + (size_t)node * INDIM;
        float acc = sb[d];
#pragma unroll
        for (int k = 0; k < INDIM; k++) acc = fmaf(xr[k], sw[d * INDIM + k], acc);
        h[(size_t)node * DIM + d] = f2bf(acc);
    }
}

// ---------------- fused layer: mean-aggregate + SAGEConv + ReLU + LayerNorm ----------------
// one 64-lane wave per node; gather pulls 16 neighbor rows (bf16, 64 B) per iteration:
// lane = slot(lane>>2) * piece(lane&3, 16 B = 8 bf16 dims). 4 waves (4 nodes) per block.

template <int LAST>
__global__ __launch_bounds__(256) void layer_kernel(
    const unsigned short* __restrict__ h_in, unsigned short* __restrict__ h_out_bf,
    float* __restrict__ h_out_f32,
    const int* __restrict__ row_ptr, const int* __restrict__ esrc,
    const float* __restrict__ wl, const float* __restrict__ bl,
    const float* __restrict__ wr, const float* __restrict__ gamma,
    const float* __restrict__ beta, int n) {
    __shared__ float sWl[DIM][DIM + 1];
    __shared__ float sWr[DIM][DIM + 1];
    __shared__ float sAgg[4][DIM];
    __shared__ float sSelf[4][DIM];
    __shared__ float sB[DIM], sG[DIM], sBe[DIM];

    int t = threadIdx.x;
    for (int i = t; i < DIM * DIM; i += 256) {
        sWl[i >> 5][i & 31] = wl[i];
        sWr[i >> 5][i & 31] = wr[i];
    }
    if (t < DIM) {
        sB[t] = bl[t];
        sG[t] = gamma[t];
        sBe[t] = beta[t];
    }
    __syncthreads();

    int lane = t & 63;
    int wv = t >> 6;
    int node = blockIdx.x * 4 + wv;
    if (node >= n) return;

    const uint4* hv = (const uint4*)h_in;  // one uint4 = 16 B = 8 bf16 dims
    int piece = lane & 3;
    int slot = lane >> 2;

    // self row -> sSelf (lanes 0-3), fp32
    if (lane < 4) {
        uint4 v = hv[(size_t)node * 4 + lane];
        float* dstp = &sSelf[wv][lane * 8];
        dstp[0] = bf2f_lo(v.x); dstp[1] = bf2f_hi(v.x);
        dstp[2] = bf2f_lo(v.y); dstp[3] = bf2f_hi(v.y);
        dstp[4] = bf2f_lo(v.z); dstp[5] = bf2f_hi(v.z);
        dstp[6] = bf2f_lo(v.w); dstp[7] = bf2f_hi(v.w);
    }

    int rs = row_ptr[node];
    int re = row_ptr[node + 1];

    // gather-sum: 16 neighbor rows in flight per iteration
    float a0 = 0.f, a1 = 0.f, a2 = 0.f, a3 = 0.f, a4 = 0.f, a5 = 0.f, a6 = 0.f, a7 = 0.f;
    for (int j = rs; j < re; j += 16) {
        int m = re - j;
        if (m > 16) m = 16;
        int se = (lane < m) ? esrc[j + lane] : 0;
        int sid = __shfl(se, slot, 64);
        if (slot < m) {
            uint4 v = hv[(size_t)sid * 4 + piece];
            a0 += bf2f_lo(v.x); a1 += bf2f_hi(v.x);
            a2 += bf2f_lo(v.y); a3 += bf2f_hi(v.y);
            a4 += bf2f_lo(v.z); a5 += bf2f_hi(v.z);
            a6 += bf2f_lo(v.w); a7 += bf2f_hi(v.w);
        }
    }
    // reduce across the 16 slots (lanes with same piece)
#pragma unroll
    for (int off = 4; off < 64; off <<= 1) {
        a0 += __shfl_xor(a0, off, 64); a1 += __shfl_xor(a1, off, 64);
        a2 += __shfl_xor(a2, off, 64); a3 += __shfl_xor(a3, off, 64);
        a4 += __shfl_xor(a4, off, 64); a5 += __shfl_xor(a5, off, 64);
        a6 += __shfl_xor(a6, off, 64); a7 += __shfl_xor(a7, off, 64);
    }
    float inv = 1.f / fmaxf((float)(re - rs), 1.f);
    if (lane < 4) {
        float* dstp = &sAgg[wv][lane * 8];
        dstp[0] = a0 * inv; dstp[1] = a1 * inv; dstp[2] = a2 * inv; dstp[3] = a3 * inv;
        dstp[4] = a4 * inv; dstp[5] = a5 * inv; dstp[6] = a6 * inv; dstp[7] = a7 * inv;
    }

    // dual matmul: lanes 0-31: b + Wl[d]·agg ; lanes 32-63: Wr[d]·self
    int d = lane & 31;
    const float* vec = (lane < 32) ? &sAgg[wv][0] : &sSelf[wv][0];
    const float* wrow = (lane < 32) ? &sWl[d][0] : &sWr[d][0];
    float o = (lane < 32) ? sB[d] : 0.f;
#pragma unroll
    for (int k = 0; k < DIM; k++) o = fmaf(vec[k], wrow[k], o);
    float oo = __shfl_xor(o, 32, 64);
    float out = o + oo;

    if (lane < 32) {
        // ReLU + LayerNorm over 32 dims
        out = fmaxf(out, 0.f);
        float sum = out, sq = out * out;
#pragma unroll
        for (int off = 16; off > 0; off >>= 1) {
            sum += __shfl_xor(sum, off, 32);
            sq += __shfl_xor(sq, off, 32);
        }
        float mu = sum * (1.f / 32.f);
        float var = fmaxf(sq * (1.f / 32.f) - mu * mu, 0.f);
        float r = rsqrtf(var + 1e-5f);
        float res = (out - mu) * r * sG[d] + sBe[d];
        if (LAST) h_out_f32[(size_t)node * DIM + d] = res;
        else      h_out_bf[(size_t)node * DIM + d] = f2bf(res);
    }
}

// ---------------- launch ----------------

extern "C" void kernel_launch(void* const* d_in, const int* in_sizes, int n_in,
                              void* d_out, int out_size, void* d_ws, size_t ws_size,
                              hipStream_t stream) {
    const float* x = (const float*)d_in[0];
    const int* ei = (const int*)d_in[1];
    const float* w_in = (const float*)d_in[2];
    const float* b_in = (const float*)d_in[3];
    const float* w_l = (const float*)d_in[4];
    const float* b_l = (const float*)d_in[5];
    const float* w_r = (const float*)d_in[6];
    const float* gamma = (const float*)d_in[7];
    const float* beta = (const float*)d_in[8];

    int n = in_sizes[0] / INDIM;
    int e = in_sizes[1] / 2;
    int L = in_sizes[4] / (DIM * DIM);
    const int* src = ei;
    const int* dst = ei + e;
    int nb = (n + 255) >> 8;  // buckets of 256 nodes

    // workspace carve
    char* w = (char*)d_ws;
    int* bcnt = (int*)w;               w += (size_t)NBMAX * 4;
    int* bbase = (int*)w;              w += (size_t)(NBMAX + 1) * 4;
    int* bcur = (int*)w;               w += (size_t)NBMAX * 4;
    int* row_ptr = (int*)w;            w += (size_t)(n + 1) * 4;
    int* esrc = (int*)w;               w += (size_t)e * 4;
    unsigned short* h_A = (unsigned short*)w;  w += (size_t)n * DIM * 2;
    unsigned short* h_B = (unsigned short*)w;  w += (size_t)n * DIM * 2;
    // packed (E*4 = 8 MB) aliases h_A+h_B (N*32*4 = 12.8 MB): dead before input_proj
    unsigned* packed = (unsigned*)h_A;

    int nbE = (e + EPB - 1) / EPB;

    hipMemsetAsync(bcnt, 0, (size_t)nb * 4, stream);
    bucket_count_kernel<<<nbE, 256, 0, stream>>>(dst, bcnt, e, nb);
    bucket_scan_kernel<<<1, 512, 0, stream>>>(bcnt, bbase, bcur, row_ptr, nb, n, e);
    bucket_fill_kernel<<<nbE, 256, 0, stream>>>(src, dst, bcur, packed, e, nb);
    csr_build_kernel<<<nb, 256, 0, stream>>>(packed, bbase, row_ptr, esrc, n);

    input_proj_kernel<<<(n * DIM + 255) / 256, 256, 0, stream>>>(x, w_in, b_in, h_A, n);

    // L=3: A->B (bf16), B->A (bf16), A->d_out (fp32)
    unsigned short* bufs[2] = {h_A, h_B};
    int nbL = (n + 3) / 4;
    for (int i = 0; i < L; i++) {
        const unsigned short* hin = bufs[i & 1];
        unsigned short* hout = bufs[(i + 1) & 1];
        const float* wl = w_l + (size_t)i * DIM * DIM;
        const float* bl = b_l + (size_t)i * DIM;
        const float* wr = w_r + (size_t)i * DIM * DIM;
        if (i == L - 1)
            layer_kernel<1><<<nbL, 256, 0, stream>>>(hin, nullptr, (float*)d_out,
                                                     row_ptr, esrc, wl, bl, wr, gamma, beta, n);
        else
            layer_kernel<0><<<nbL, 256, 0, stream>>>(hin, hout, nullptr,
                                                     row_ptr, esrc, wl, bl, wr, gamma, beta, n);
    }
}

// Round 4
// 310.841 us; speedup vs baseline: 1.8482x; 1.1365x over previous
//
#include <hip/hip_runtime.h>
#include <hip/hip_bf16.h>

#define DIM 32
#define INDIM 5
#define EPB 4096      // edges per block in bucketing passes
#define NBMAX 512     // max buckets (n <= 131072)
#define CAP 8192      // P2 LDS staging capacity (mean bucket load ~5120)
#define NPW 8         // nodes per wave in layer kernel

// bf16 helpers (bit-level, round-to-nearest-even)
__device__ __forceinline__ unsigned short f2bf(float f) {
    unsigned u = __float_as_uint(f);
    u += 0x7FFFu + ((u >> 16) & 1u);
    return (unsigned short)(u >> 16);
}
__device__ __forceinline__ float bf2f_lo(unsigned u) { return __uint_as_float(u << 16); }
__device__ __forceinline__ float bf2f_hi(unsigned u) { return __uint_as_float(u & 0xFFFF0000u); }

// ---------------- P0: bucket sizes ----------------

__global__ __launch_bounds__(256) void bucket_count_kernel(const int* __restrict__ dst,
                                                           int* __restrict__ bcnt, int e, int nb) {
    __shared__ int hist[NBMAX];
    int t = threadIdx.x;
    for (int i = t; i < nb; i += 256) hist[i] = 0;
    __syncthreads();
    int base = blockIdx.x * EPB;
    for (int k = 0; k < EPB; k += 256) {
        int i = base + k + t;
        if (i < e) atomicAdd(&hist[dst[i] >> 8], 1);
    }
    __syncthreads();
    for (int i = t; i < nb; i += 256) {
        int h = hist[i];
        if (h) atomicAdd(&bcnt[i], h);
    }
}

// ---------------- scan of bucket sizes (single block) ----------------

__global__ void bucket_scan_kernel(const int* __restrict__ bcnt, int* __restrict__ bbase,
                                   int* __restrict__ bcur, int* __restrict__ row_ptr,
                                   int nb, int n, int e) {
    __shared__ int s[512];
    int t = threadIdx.x;
    int v = (t < nb) ? bcnt[t] : 0;
    s[t] = v;
    __syncthreads();
    for (int o = 1; o < 512; o <<= 1) {
        int a = (t >= o) ? s[t - o] : 0;
        __syncthreads();
        s[t] += a;
        __syncthreads();
    }
    if (t < nb) {
        int excl = s[t] - v;
        bbase[t] = excl;
        bcur[t] = excl;
    }
    if (t == 0) {
        bbase[nb] = e;
        row_ptr[n] = e;
    }
}

// ---------------- P1: bucketed scatter of packed edges ----------------
// packed word: (src << 8) | (dst & 255)

__global__ __launch_bounds__(256) void bucket_fill_kernel(const int* __restrict__ src,
                                                          const int* __restrict__ dst,
                                                          int* __restrict__ bcur,
                                                          unsigned* __restrict__ packed,
                                                          int e, int nb) {
    __shared__ unsigned sw[EPB];
    __shared__ unsigned short sb[EPB];
    __shared__ int hist[NBMAX];
    __shared__ int rbase[NBMAX];
    int t = threadIdx.x;
    for (int i = t; i < nb; i += 256) hist[i] = 0;
    __syncthreads();
    int base = blockIdx.x * EPB;
    for (int k = 0; k < EPB; k += 256) {
        int i = base + k + t;
        if (i < e) {
            int s = src[i];
            int d = dst[i];
            int b = d >> 8;
            sw[k + t] = ((unsigned)s << 8) | (unsigned)(d & 255);
            sb[k + t] = (unsigned short)b;
            atomicAdd(&hist[b], 1);
        }
    }
    __syncthreads();
    for (int i = t; i < nb; i += 256) {
        int h = hist[i];
        rbase[i] = h ? atomicAdd(&bcur[i], h) : 0;
        hist[i] = 0;  // reuse as rank counter
    }
    __syncthreads();
    for (int k = 0; k < EPB; k += 256) {
        int i = base + k + t;
        if (i < e) {
            int b = sb[k + t];
            int r = atomicAdd(&hist[b], 1);
            packed[rbase[b] + r] = sw[k + t];
        }
    }
}

// ---------------- P2: per-bucket counting sort -> exact CSR ----------------

__global__ __launch_bounds__(256) void csr_build_kernel(const unsigned* __restrict__ packed,
                                                        const int* __restrict__ bbase,
                                                        int* __restrict__ row_ptr,
                                                        int* __restrict__ esrc, int n) {
    __shared__ unsigned ew[CAP];
    __shared__ int h2[256];
    __shared__ int off[256];
    int b = blockIdx.x;
    int base = bbase[b];
    int cnt = bbase[b + 1] - base;
    int t = threadIdx.x;
    h2[t] = 0;
    __syncthreads();
    bool staged = (cnt <= CAP);
    for (int i = t; i < cnt; i += 256) {
        unsigned w = packed[base + i];
        if (staged) ew[i] = w;
        atomicAdd(&h2[w & 255], 1);
    }
    __syncthreads();
    int v = h2[t];
    off[t] = v;
    __syncthreads();
    for (int o = 1; o < 256; o <<= 1) {
        int a = (t >= o) ? off[t - o] : 0;
        __syncthreads();
        off[t] += a;
        __syncthreads();
    }
    int excl = off[t] - v;
    __syncthreads();
    off[t] = excl;
    h2[t] = 0;  // reuse as rank counter
    __syncthreads();
    int node = b * 256 + t;
    if (node < n) row_ptr[node] = base + excl;
    for (int i = t; i < cnt; i += 256) {
        unsigned w = staged ? ew[i] : packed[base + i];
        int dl = w & 255;
        int r = atomicAdd(&h2[dl], 1);
        esrc[base + off[dl] + r] = (int)(w >> 8);
    }
}

// ---------------- input projection: h = x @ w_in.T + b_in (bf16 out) ----------------

__global__ void input_proj_kernel(const float* __restrict__ x, const float* __restrict__ w_in,
                                  const float* __restrict__ b_in,
                                  unsigned short* __restrict__ h, int n) {
    __shared__ float sw[DIM * INDIM];
    __shared__ float sb[DIM];
    int t = threadIdx.x;
    if (t < DIM * INDIM) sw[t] = w_in[t];
    if (t < DIM) sb[t] = b_in[t];
    __syncthreads();
    int idx = blockIdx.x * 256 + t;
    int node = idx >> 5;
    int d = idx & 31;
    if (node < n) {
        const float* xr = x + (size_t)node * INDIM;
        float acc = sb[d];
#pragma unroll
        for (int k = 0; k < INDIM; k++) acc = fmaf(xr[k], sw[d * INDIM + k], acc);
        h[(size_t)node * DIM + d] = f2bf(acc);
    }
}

// ---------------- fused layer: mean-aggregate + SAGEConv + ReLU + LayerNorm ----------------
// 4 waves/block, each wave loops over NPW consecutive nodes.
// Weights in registers (lane d<32: Wl row d; lane>=32: Wr row d).
// Gather: 8 slots x 8 pieces (uint2 = 4 bf16 dims/lane), 8 rows per VMEM instr.

template <int LAST>
__global__ __launch_bounds__(256) void layer_kernel(
    const unsigned short* __restrict__ h_in, unsigned short* __restrict__ h_out_bf,
    float* __restrict__ h_out_f32,
    const int* __restrict__ row_ptr, const int* __restrict__ esrc,
    const float* __restrict__ wl, const float* __restrict__ bl,
    const float* __restrict__ wr, const float* __restrict__ gamma,
    const float* __restrict__ beta, int n) {
    __shared__ float sVec[4][2][2][DIM];  // [wave][parity][agg|self][dim]

    int t = threadIdx.x;
    int lane = t & 63;
    int wv = t >> 6;
    int d = lane & 31;

    // weight row in registers
    const float* wsrc = (lane < 32) ? wl : wr;
    float wreg[DIM];
    {
        const float4* wp = (const float4*)(wsrc + d * DIM);
#pragma unroll
        for (int q = 0; q < 8; q++) {
            float4 v = wp[q];
            wreg[4 * q] = v.x; wreg[4 * q + 1] = v.y;
            wreg[4 * q + 2] = v.z; wreg[4 * q + 3] = v.w;
        }
    }
    float bias = (lane < 32) ? bl[d] : 0.f;
    float g = gamma[d], be = beta[d];

    int piece = lane & 7;   // 4 dims each (8 B)
    int slot = lane >> 3;   // 8 edge slots

    int base = blockIdx.x * (4 * NPW) + wv * NPW;
    const uint2* hv2 = (const uint2*)h_in;

    for (int it = 0; it < NPW; ++it) {
        int node = base + it;
        if (node >= n) break;  // wave-uniform
        int par = it & 1;
        int rs = row_ptr[node];
        int re = row_ptr[node + 1];
        int deg = re - rs;

        // self row: lanes 8-15 fetch piece (lane-8) early, stash fp32 to LDS
        if (lane >= 8 && lane < 16) {
            uint2 v = hv2[(size_t)node * 8 + (lane - 8)];
            float4 f;
            f.x = bf2f_lo(v.x); f.y = bf2f_hi(v.x);
            f.z = bf2f_lo(v.y); f.w = bf2f_hi(v.y);
            *(float4*)&sVec[wv][par][1][(lane - 8) * 4] = f;
        }

        // gather-sum: 8 neighbor rows per step, up to 4 steps per 32-edge window
        float a0 = 0.f, a1 = 0.f, a2 = 0.f, a3 = 0.f;
        for (int w0 = rs; w0 < re; w0 += 32) {
            int rem = re - w0;
            if (rem > 32) rem = 32;
            int se = (lane < rem) ? esrc[w0 + lane] : 0;
#pragma unroll
            for (int q = 0; q < 4; q++) {
                if (q * 8 >= rem) break;  // wave-uniform
                int sid = __shfl(se, q * 8 + slot, 64);
                if (q * 8 + slot < rem) {
                    uint2 v = hv2[(size_t)sid * 8 + piece];
                    a0 += bf2f_lo(v.x); a1 += bf2f_hi(v.x);
                    a2 += bf2f_lo(v.y); a3 += bf2f_hi(v.y);
                }
            }
        }
        // reduce across 8 slots (lane bits 3,4,5)
#pragma unroll
        for (int off = 8; off < 64; off <<= 1) {
            a0 += __shfl_xor(a0, off, 64);
            a1 += __shfl_xor(a1, off, 64);
            a2 += __shfl_xor(a2, off, 64);
            a3 += __shfl_xor(a3, off, 64);
        }
        float inv = 1.f / fmaxf((float)deg, 1.f);
        if (lane < 8) {
            float4 f;
            f.x = a0 * inv; f.y = a1 * inv; f.z = a2 * inv; f.w = a3 * inv;
            *(float4*)&sVec[wv][par][0][lane * 4] = f;
        }
        asm volatile("s_waitcnt lgkmcnt(0)" ::: "memory");
        __builtin_amdgcn_sched_barrier(0);

        // dual matvec: lanes 0-31: b + Wl[d]·agg ; lanes 32-63: Wr[d]·self
        float o = bias;
        const float4* vp = (const float4*)&sVec[wv][par][lane >> 5][0];
#pragma unroll
        for (int q = 0; q < 8; q++) {
            float4 v = vp[q];
            o = fmaf(v.x, wreg[4 * q], o);
            o = fmaf(v.y, wreg[4 * q + 1], o);
            o = fmaf(v.z, wreg[4 * q + 2], o);
            o = fmaf(v.w, wreg[4 * q + 3], o);
        }
        float out = o + __shfl_xor(o, 32, 64);

        if (lane < 32) {
            out = fmaxf(out, 0.f);
            float sum = out, sq = out * out;
#pragma unroll
            for (int off = 16; off > 0; off >>= 1) {
                sum += __shfl_xor(sum, off, 32);
                sq += __shfl_xor(sq, off, 32);
            }
            float mu = sum * (1.f / 32.f);
            float var = fmaxf(sq * (1.f / 32.f) - mu * mu, 0.f);
            float r = rsqrtf(var + 1e-5f);
            float res = (out - mu) * r * g + be;
            if (LAST) h_out_f32[(size_t)node * DIM + d] = res;
            else      h_out_bf[(size_t)node * DIM + d] = f2bf(res);
        }
    }
}

// ---------------- launch ----------------

extern "C" void kernel_launch(void* const* d_in, const int* in_sizes, int n_in,
                              void* d_out, int out_size, void* d_ws, size_t ws_size,
                              hipStream_t stream) {
    const float* x = (const float*)d_in[0];
    const int* ei = (const int*)d_in[1];
    const float* w_in = (const float*)d_in[2];
    const float* b_in = (const float*)d_in[3];
    const float* w_l = (const float*)d_in[4];
    const float* b_l = (const float*)d_in[5];
    const float* w_r = (const float*)d_in[6];
    const float* gamma = (const float*)d_in[7];
    const float* beta = (const float*)d_in[8];

    int n = in_sizes[0] / INDIM;
    int e = in_sizes[1] / 2;
    int L = in_sizes[4] / (DIM * DIM);
    const int* src = ei;
    const int* dst = ei + e;
    int nb = (n + 255) >> 8;  // buckets of 256 nodes

    // workspace carve
    char* w = (char*)d_ws;
    int* bcnt = (int*)w;               w += (size_t)NBMAX * 4;
    int* bbase = (int*)w;              w += (size_t)(NBMAX + 1) * 4;
    int* bcur = (int*)w;               w += (size_t)NBMAX * 4;
    int* row_ptr = (int*)w;            w += (size_t)(n + 1) * 4;
    int* esrc = (int*)w;               w += (size_t)e * 4;
    unsigned short* h_A = (unsigned short*)w;  w += (size_t)n * DIM * 2;
    unsigned short* h_B = (unsigned short*)w;  w += (size_t)n * DIM * 2;
    // packed (E*4 = 8 MB) aliases h_A+h_B (N*32*4 = 12.8 MB): dead before input_proj
    unsigned* packed = (unsigned*)h_A;

    int nbE = (e + EPB - 1) / EPB;

    hipMemsetAsync(bcnt, 0, (size_t)nb * 4, stream);
    bucket_count_kernel<<<nbE, 256, 0, stream>>>(dst, bcnt, e, nb);
    bucket_scan_kernel<<<1, 512, 0, stream>>>(bcnt, bbase, bcur, row_ptr, nb, n, e);
    bucket_fill_kernel<<<nbE, 256, 0, stream>>>(src, dst, bcur, packed, e, nb);
    csr_build_kernel<<<nb, 256, 0, stream>>>(packed, bbase, row_ptr, esrc, n);

    input_proj_kernel<<<(n * DIM + 255) / 256, 256, 0, stream>>>(x, w_in, b_in, h_A, n);

    // L=3: A->B (bf16), B->A (bf16), A->d_out (fp32)
    unsigned short* bufs[2] = {h_A, h_B};
    int nbL = (n + 4 * NPW - 1) / (4 * NPW);
    for (int i = 0; i < L; i++) {
        const unsigned short* hin = bufs[i & 1];
        unsigned short* hout = bufs[(i + 1) & 1];
        const float* wl = w_l + (size_t)i * DIM * DIM;
        const float* bl = b_l + (size_t)i * DIM;
        const float* wr = w_r + (size_t)i * DIM * DIM;
        if (i == L - 1)
            layer_kernel<1><<<nbL, 256, 0, stream>>>(hin, nullptr, (float*)d_out,
                                                     row_ptr, esrc, wl, bl, wr, gamma, beta, n);
        else
            layer_kernel<0><<<nbL, 256, 0, stream>>>(hin, hout, nullptr,
                                                     row_ptr, esrc, wl, bl, wr, gamma, beta, n);
    }
}